// Round 10
// baseline (1186.039 us; speedup 1.0000x reference)
//
#include <hip/hip_runtime.h>
#include <stdint.h>
#include <stddef.h>

// ---------------------------------------------------------------------------
// EnhancedSpatialAttention, round 10 (MI355X / gfx950).
// K2 rebuilt around the r7-r9 invariants (2 blocks/CU + duplicated B-reads):
//  - wave grid 1M(64 rows)x4N(16 cols), kc=64 -> 8KB weight chunks, ZERO
//    B-read duplication (8KB read + 8KB DMA per block per body).
//  - A-frags (xa[8], 32 VGPR) loaded per kc straight from unit-major xbf in
//    global (L1-shared across the 4 waves); no x LDS stage.
//  - LDS 48KB static (ring-3 x 8KB + B0/B1/B2) -> 3 blocks/CU (50% more TLP).
//  - ring-3 constant slots (Q:0 K:1 V:2), stage-1-ahead, counted vmcnt
//    (Q:10, K/V:2), 1 barrier/body; A-loads issued BEFORE the stage so the
//    compiler's A-wait is vmcnt(2), not a queue drain (sched_barrier pins it).
// prep: QKV chunks re-tiled to 192 x 8KB (kc-major); x -> 8 x 8KB unit-major
// quarters in d_out back half. K3 oproj_ln: unchanged (HBM floor).
// ---------------------------------------------------------------------------

typedef __attribute__((ext_vector_type(8))) short short8;    // 8 bf16
typedef __attribute__((ext_vector_type(4))) float f32x4;     // MFMA C/D frag

typedef __attribute__((address_space(3))) unsigned int as3_u32;
typedef __attribute__((address_space(1))) unsigned int as1_u32;

#define VMCNT10 asm volatile("s_waitcnt vmcnt(10)" ::: "memory")
#define VMCNT5  asm volatile("s_waitcnt vmcnt(5)" ::: "memory")
#define VMCNT2  asm volatile("s_waitcnt vmcnt(2)" ::: "memory")
#define VMCNT0  asm volatile("s_waitcnt vmcnt(0)" ::: "memory")
#define LGKM0   asm volatile("s_waitcnt lgkmcnt(0)" ::: "memory")
#define BARR()  __builtin_amdgcn_s_barrier()
#define SCHEDB  __builtin_amdgcn_sched_barrier(0)
#define PRIO1   __builtin_amdgcn_s_setprio(1)
#define PRIO0   __builtin_amdgcn_s_setprio(0)

__device__ __forceinline__ unsigned short f2bf(float f) {
  unsigned u = __builtin_bit_cast(unsigned, f);
  u = (u + 0x7FFFu + ((u >> 16) & 1u)) >> 16;   // RNE
  return (unsigned short)u;
}

__device__ __forceinline__ f32x4 mfma16(short8 a, short8 b, f32x4 c) {
  return __builtin_amdgcn_mfma_f32_16x16x32_bf16(a, b, c, 0, 0, 0);
}

// 64-row x 64-col bf16 scratch, 128B row stride, 16B-unit XOR swizzle.
__device__ __forceinline__ short8 rd8s(const char* buf, int row, int unit) {
  return *(const short8*)(buf + row * 128 + ((unit ^ (row & 7)) * 16));
}
__device__ __forceinline__ void wr2s(char* buf, int row, int col, unsigned short v) {
  int slot = (col >> 3) ^ (row & 7);
  *(unsigned short*)(buf + row * 128 + slot * 16 + (col & 7) * 2) = v;
}
__device__ __forceinline__ void wr8s(char* buf, int row, int col, uint2 v) {
  int slot = (col >> 3) ^ (row & 7);
  *(uint2*)(buf + row * 128 + slot * 16 + (col & 7) * 2) = v;
}

// Stage one 8KB chunk: 2 x global_load_lds dwordx4 per thread, linear LDS.
__device__ __forceinline__ void stage8k(char* ldsbase, const char* gsrc, int w, int lane) {
#pragma unroll
  for (int j = 0; j < 2; ++j) {
    int off = j * 4096 + w * 1024;
    __builtin_amdgcn_global_load_lds((const as1_u32*)(gsrc + off + lane * 16),
                                     (as3_u32*)(ldsbase + off), 16, 0, 0);
  }
}

// Stage one 16KB chunk (K3 path, unchanged).
__device__ __forceinline__ void stage16k(char* ldsbase, const char* gsrc, int w, int lane) {
#pragma unroll
  for (int j = 0; j < 4; ++j) {
    int off = j * 4096 + w * 1024;
    __builtin_amdgcn_global_load_lds((const as1_u32*)(gsrc + off + lane * 16),
                                     (as3_u32*)(ldsbase + off), 16, 0, 0);
  }
}

// ============================ prep =========================================
// grid: [0,8192) x chunks (2x8KB/block) | [8192,8288) QKV chunks (2x8KB/block)
//       | [8288,8320) Wo 16KB chunks | [8320,8336) bias
__global__ void prep_kernel(const float* __restrict__ x,
                            const float* __restrict__ wqkv_f,
                            const float* __restrict__ wo_f,
                            const float* __restrict__ rel,
                            unsigned short* __restrict__ wt,
                            float* __restrict__ bias2d,
                            char* __restrict__ dout) {
  int b = blockIdx.x, tid = threadIdx.x;
  if (b < 8192) {
    // x: seq n, chunk pair p -> chunks 2p,2p+1 (each 64 rows x 64 k, unit-major)
    int n = b >> 2, p = b & 3;
    char* dstb = dout + (size_t)n * 131072 + 65536;
    const float* srcb = x + (size_t)n * 32768;
#pragma unroll
    for (int t = 0; t < 4; ++t) {
      int flat = t * 256 + tid;          // 16B unit of the 16KB pair
      int c = p * 2 + (flat >> 9);
      int r512 = flat & 511;
      int row = r512 >> 3, u = r512 & 7;
      const float* src = srcb + row * 512 + c * 64 + u * 8;
      float4 a = *(const float4*)src;
      float4 cc = *(const float4*)(src + 4);
      unsigned p0 = (unsigned)f2bf(a.x) | ((unsigned)f2bf(a.y) << 16);
      unsigned p1 = (unsigned)f2bf(a.z) | ((unsigned)f2bf(a.w) << 16);
      unsigned p2 = (unsigned)f2bf(cc.x) | ((unsigned)f2bf(cc.y) << 16);
      unsigned p3 = (unsigned)f2bf(cc.z) | ((unsigned)f2bf(cc.w) << 16);
      *(uint4*)(dstb + c * 8192 + u * 1024 + row * 16) = make_uint4(p0, p1, p2, p3);
    }
  } else if (b < 8288) {
    // QKV chunk pair: chunks (b-8192)*2 + {0,1}; chunk = 64 outcols x 64 k,
    // source pre-inverse-swizzled so linear LDS write + swizzled read works.
    int cb2 = (b - 8192) * 2;
#pragma unroll
    for (int t = 0; t < 4; ++t) {
      int flat = t * 256 + tid;
      int c = cb2 + (flat >> 9);
      int r512 = flat & 511;
      int row = r512 >> 3, us = r512 & 7;
      int kg = us ^ (row & 7);
      int h = c / 24, j = c % 24;
      int kc = j / 3, rg = j % 3;
      const float* src =
          wqkv_f + (size_t)(rg * 512 + h * 64 + row) * 512 + kc * 64 + kg * 8;
      float4 a = *(const float4*)src;
      float4 cc = *(const float4*)(src + 4);
      unsigned p0 = (unsigned)f2bf(a.x) | ((unsigned)f2bf(a.y) << 16);
      unsigned p1 = (unsigned)f2bf(a.z) | ((unsigned)f2bf(a.w) << 16);
      unsigned p2 = (unsigned)f2bf(cc.x) | ((unsigned)f2bf(cc.y) << 16);
      unsigned p3 = (unsigned)f2bf(cc.z) | ((unsigned)f2bf(cc.w) << 16);
      *(uint4*)(wt + (size_t)c * 4096 + r512 * 8) = make_uint4(p0, p1, p2, p3);
    }
  } else if (b < 8320) {
    // Wo chunk: 16KB, identical layout to r9 (K3 unchanged).
    int cw = b - 8288;
    unsigned short* dst = wt + 786432 + (size_t)cw * 8192;
#pragma unroll
    for (int t = 0; t < 4; ++t) {
      int u = t * 256 + tid;
      int row = u >> 4, us = u & 15;
      int kg = (us & 8) | ((us ^ row) & 7);
      int kcw = cw >> 3, ng = cw & 7;
      const float* src = wo_f + (size_t)(ng * 64 + row) * 512 + kcw * 128 + kg * 8;
      float4 a = *(const float4*)src;
      float4 cc = *(const float4*)(src + 4);
      unsigned p0 = (unsigned)f2bf(a.x) | ((unsigned)f2bf(a.y) << 16);
      unsigned p1 = (unsigned)f2bf(a.z) | ((unsigned)f2bf(a.w) << 16);
      unsigned p2 = (unsigned)f2bf(cc.x) | ((unsigned)f2bf(cc.y) << 16);
      unsigned p3 = (unsigned)f2bf(cc.z) | ((unsigned)f2bf(cc.w) << 16);
      *(uint4*)(dst + u * 8) = make_uint4(p0, p1, p2, p3);
    }
  } else {
    int idx = (b - 8320) * 256 + tid;  // 0..4095
    int m = idx >> 6, nn = idx & 63;
    float s = 0.f;
#pragma unroll
    for (int hh = 0; hh < 8; ++hh) s += rel[hh * 16384 + m * 128 + nn];
    bias2d[idx] = s * 0.125f;
  }
}

// ============================ K2: attn_qkv =================================
__global__ __launch_bounds__(256, 3) void attn_qkv(
    const char* __restrict__ wq,        // 192 x 8KB QKV chunks (kc-major)
    const float* __restrict__ bqkv,     // [1536]
    const float* __restrict__ bias2d,   // [64,64]
    char* __restrict__ ctxg) {          // d_out stripes: [ctx 64KB | xbf 64KB]
  __shared__ __attribute__((aligned(16))) char smem[49152];
  char* RING = smem;               // 3 x 8KB (Q reads slot0, K slot1, V slot2)
  char* B0 = smem + 24576;         // Q, then P (8KB swizzled)
  char* B1 = smem + 32768;         // K, then ctx
  char* B2 = smem + 40960;         // V^T

  const int n = blockIdx.x;
  const int tid = threadIdx.x;
  const int w = tid >> 6, lane = tid & 63;
  const int l15 = lane & 15, g = lane >> 4;
  const int wn = w;                    // proj wave grid 1M x 4N: 16 cols/wave
  const int brow = wn * 16 + l15;      // B-frag row (weight out-col)
  const int mrow = w * 16 + g * 4;     // attn-phase C rows
  const int wrow = w * 16 + l15;       // attn-phase A row
  const int us0 = (g ^ (brow & 7)) * 16;        // const swizzled offsets
  const int us1 = ((4 + g) ^ (brow & 7)) * 16;

  const char* xsrc = ctxg + (size_t)n * 131072 + 65536;  // unit-major xbf

  // bias2d -> regs; drain queue so the counted loop sees staging loads only.
  float b2d[16];
#pragma unroll
  for (int nt = 0; nt < 4; ++nt)
#pragma unroll
    for (int r = 0; r < 4; ++r)
      b2d[nt * 4 + r] = bias2d[(mrow + r) * 64 + nt * 16 + l15];
  VMCNT0;

  stage8k(RING, wq, w, lane);          // chunk 0 -> slot 0

  for (int h = 0; h < 8; ++h) {
    f32x4 aq[4] = {}, ak[4] = {}, av[4] = {};
#pragma unroll
    for (int kc = 0; kc < 8; ++kc) {
      const int cb = h * 24 + kc * 3;
      // ---------------- Q body: reads slot0 (w[cb]) + xa(kc) ----------------
      short8 xa[8];
#pragma unroll
      for (int mt = 0; mt < 4; ++mt)
#pragma unroll
        for (int ks = 0; ks < 2; ++ks)
          xa[mt * 2 + ks] = *(const short8*)(xsrc + kc * 8192 +
                                             (ks * 4 + g) * 1024 +
                                             (mt * 16 + l15) * 16);
      SCHEDB;  // keep xa-loads older than the stage (compiler A-wait = vmcnt(2))
      stage8k(RING + 8192, wq + (size_t)(cb + 1) * 8192, w, lane);
      VMCNT10; BARR();   // drains w[cb] (+ any older stores)
      {
        short8 bf0 = *(const short8*)(RING + brow * 128 + us0);
        short8 bf1 = *(const short8*)(RING + brow * 128 + us1);
        PRIO1;
#pragma unroll
        for (int mt = 0; mt < 4; ++mt) {
          aq[mt] = mfma16(xa[mt * 2], bf0, aq[mt]);
          aq[mt] = mfma16(xa[mt * 2 + 1], bf1, aq[mt]);
        }
        PRIO0;
      }
      // ---------------- K body: reads slot1 (w[cb+1]) ----------------
      stage8k(RING + 16384, wq + (size_t)(cb + 2) * 8192, w, lane);
      VMCNT2; BARR();
      {
        short8 bf0 = *(const short8*)(RING + 8192 + brow * 128 + us0);
        short8 bf1 = *(const short8*)(RING + 8192 + brow * 128 + us1);
        PRIO1;
#pragma unroll
        for (int mt = 0; mt < 4; ++mt) {
          ak[mt] = mfma16(xa[mt * 2], bf0, ak[mt]);
          ak[mt] = mfma16(xa[mt * 2 + 1], bf1, ak[mt]);
        }
        PRIO0;
      }
      // ---------------- V body: reads slot2 (w[cb+2]) ----------------
      if (cb + 3 < 192) {
        stage8k(RING, wq + (size_t)(cb + 3) * 8192, w, lane);
        VMCNT2;
      } else {
        VMCNT0;
      }
      BARR();
      {
        short8 bf0 = *(const short8*)(RING + 16384 + brow * 128 + us0);
        short8 bf1 = *(const short8*)(RING + 16384 + brow * 128 + us1);
        PRIO1;
#pragma unroll
        for (int mt = 0; mt < 4; ++mt) {
          av[mt] = mfma16(xa[mt * 2], bf0, av[mt]);
          av[mt] = mfma16(xa[mt * 2 + 1], bf1, av[mt]);
        }
        PRIO0;
      }
    }

    // ---------- head writeback: Q->B0, K->B1, Vt->B2 ----------
    {
      int col = wn * 16 + l15;
      float bq = bqkv[h * 64 + col];
      float bk = bqkv[512 + h * 64 + col];
      float bv = bqkv[1024 + h * 64 + col];
#pragma unroll
      for (int mt = 0; mt < 4; ++mt) {
        int rowb = mt * 16 + g * 4;
#pragma unroll
        for (int r = 0; r < 4; ++r) {
          wr2s(B0, rowb + r, col, f2bf(aq[mt][r] + bq));
          wr2s(B1, rowb + r, col, f2bf(ak[mt][r] + bk));
        }
        unsigned short p0 = f2bf(av[mt][0] + bv);
        unsigned short p1 = f2bf(av[mt][1] + bv);
        unsigned short p2 = f2bf(av[mt][2] + bv);
        unsigned short p3 = f2bf(av[mt][3] + bv);
        unsigned lo = (unsigned)p0 | ((unsigned)p1 << 16);
        unsigned hi = (unsigned)p2 | ((unsigned)p3 << 16);
        wr8s(B2, col, rowb, make_uint2(lo, hi));   // Vt[d][tok]
      }
    }
    LGKM0; BARR();   // Q/K/Vt visible to all waves

    // ---- scores + softmax: P -> B0 (wave-own rows)
    {
      f32x4 sc[4] = {};
      short8 aq0 = rd8s(B0, wrow, g);
      short8 aq1 = rd8s(B0, wrow, 4 + g);
#pragma unroll
      for (int nt = 0; nt < 4; ++nt)
        sc[nt] = mfma16(aq0, rd8s(B1, nt * 16 + l15, g), sc[nt]);
#pragma unroll
      for (int nt = 0; nt < 4; ++nt)
        sc[nt] = mfma16(aq1, rd8s(B1, nt * 16 + l15, 4 + g), sc[nt]);
      float mx[4] = {-1e30f, -1e30f, -1e30f, -1e30f};
#pragma unroll
      for (int nt = 0; nt < 4; ++nt)
#pragma unroll
        for (int r = 0; r < 4; ++r) {
          float v = sc[nt][r] * 0.125f + b2d[nt * 4 + r];
          sc[nt][r] = v;
          mx[r] = fmaxf(mx[r], v);
        }
#pragma unroll
      for (int mk = 1; mk < 16; mk <<= 1)
#pragma unroll
        for (int r = 0; r < 4; ++r) mx[r] = fmaxf(mx[r], __shfl_xor(mx[r], mk));
      float sm[4] = {0.f, 0.f, 0.f, 0.f};
#pragma unroll
      for (int nt = 0; nt < 4; ++nt)
#pragma unroll
        for (int r = 0; r < 4; ++r) {
          float e = __expf(sc[nt][r] - mx[r]);
          sc[nt][r] = e;
          sm[r] += e;
        }
#pragma unroll
      for (int mk = 1; mk < 16; mk <<= 1)
#pragma unroll
        for (int r = 0; r < 4; ++r) sm[r] += __shfl_xor(sm[r], mk);
      float inv[4];
#pragma unroll
      for (int r = 0; r < 4; ++r) inv[r] = 1.0f / sm[r];
#pragma unroll
      for (int nt = 0; nt < 4; ++nt)
#pragma unroll
        for (int r = 0; r < 4; ++r)
          wr2s(B0, mrow + r, nt * 16 + l15, f2bf(sc[nt][r] * inv[r]));
    }

    // ---- PV (P own rows in-wave; Vt stable since writeback barrier)
    f32x4 cv[4] = {};
    {
      short8 ap0 = rd8s(B0, wrow, g);
      short8 ap1 = rd8s(B0, wrow, 4 + g);
#pragma unroll
      for (int nt = 0; nt < 4; ++nt)
        cv[nt] = mfma16(ap0, rd8s(B2, nt * 16 + l15, g), cv[nt]);
#pragma unroll
      for (int nt = 0; nt < 4; ++nt)
        cv[nt] = mfma16(ap1, rd8s(B2, nt * 16 + l15, 4 + g), cv[nt]);
    }
    BARR();   // all waves' K reads (scores) done before ctx overwrites B1
#pragma unroll
    for (int nt = 0; nt < 4; ++nt)
#pragma unroll
      for (int r = 0; r < 4; ++r)
        wr2s(B1, mrow + r, nt * 16 + l15, f2bf(cv[nt][r]));
    LGKM0; BARR();

    // ---- ctx copyout: contiguous 8KB/head into stripe front half
    {
      char* cdst = ctxg + (size_t)n * 131072 + h * 8192;
#pragma unroll
      for (int it = 0; it < 2; ++it) {
        int flat = it * 256 + tid;
        int row = flat >> 3, s = flat & 7;
        uint4 v = *(const uint4*)(B1 + row * 128 + s * 16);
        *(uint4*)(cdst + row * 128 + s * 16) = v;
      }
    }
  }
}

// ============================ K3: oproj_ln (unchanged) =====================
__global__ __launch_bounds__(256, 2) void oproj_ln(
    const char* __restrict__ ctxg,      // 8KB/head ctx blocks in d_out stripes
    const char* __restrict__ wo,        // 32 x 16KB Wo chunks
    const float* __restrict__ bo,
    const float* __restrict__ x,
    const float* __restrict__ lng,
    const float* __restrict__ lnb,
    float* __restrict__ out) {
  __shared__ __attribute__((aligned(16))) char smem[65536];
  char* WB = smem;            // 2 x 16KB Wo stage
  char* CB = smem + 32768;    // 2 x 16KB ctx stage
  float* EP  = (float*)smem;           // epilogue [64][68] f32 (overlays WB)
  float* SM1 = (float*)(smem + 32768); // [64][2] partials (overlays CB)
  float* SM2 = (float*)(smem + 33408);

  const int n = blockIdx.x;
  const int tid = threadIdx.x;
  const int w = tid >> 6, lane = tid & 63;
  const int l15 = lane & 15, g = lane >> 4;
  const int um = w >> 1, un = w & 1;

  const char* cbase = ctxg + (size_t)n * 131072;

  stage16k(CB, cbase, w, lane);
  stage16k(WB, wo, w, lane);

  f32x4 acc[8][2][2] = {};

  for (int kc = 0; kc < 4; ++kc) {
    short8 actx[2][4];
#pragma unroll
    for (int ng = 0; ng < 8; ++ng) {
      int b = kc * 8 + ng;
      if (b < 31)
        stage16k(WB + (((b + 1) & 1) << 14), wo + (size_t)(b + 1) * 16384, w, lane);
      if ((ng & 1) == 0 && kc < 3) {
        int p = ng >> 1;
        int off = p * 4096 + w * 1024;
        __builtin_amdgcn_global_load_lds(
            (const as1_u32*)(cbase + (kc + 1) * 16384 + off + lane * 16),
            (as3_u32*)(CB + (((kc + 1) & 1) << 14) + off), 16, 0, 0);
      }
      if (b < 31) { VMCNT5; } else { VMCNT0; }
      BARR();
      const char* cb = CB + ((kc & 1) << 14);
      if (ng == 0) {
#pragma unroll
        for (int mt = 0; mt < 2; ++mt)
#pragma unroll
          for (int ks = 0; ks < 4; ++ks) {
            int row = um * 32 + mt * 16 + l15;
            int u = ks * 4 + g;
            actx[mt][ks] = *(const short8*)(cb + (u >> 3) * 8192 + row * 128 +
                                            (((u & 7) ^ (row & 7)) * 16));
          }
      }
      const char* ws = WB + ((b & 1) << 14);
      PRIO1;
#pragma unroll
      for (int ks = 0; ks < 4; ++ks) {
#pragma unroll
        for (int nt = 0; nt < 2; ++nt) {
          int row = un * 32 + nt * 16 + l15;
          int kg = ks * 4 + g;
          int us = (kg & 8) | ((kg ^ row) & 7);
          short8 bfr = *(const short8*)(ws + row * 256 + us * 16);
          acc[ng][0][nt] = mfma16(actx[0][ks], bfr, acc[ng][0][nt]);
          acc[ng][1][nt] = mfma16(actx[1][ks], bfr, acc[ng][1][nt]);
        }
      }
      PRIO0;
      BARR();
    }
  }

  // ================= epilogue: +bo, +residual, LayerNorm ===================
  VMCNT0;
  const float* xblk = x + (size_t)n * 32768;
  float* oblk = out + (size_t)n * 32768;
  float s1[2][4] = {}, s2[2][4] = {};

#pragma unroll
  for (int ng = 0; ng < 8; ++ng) {
#pragma unroll
    for (int t = 0; t < 4; ++t) {
      int flat = t * 256 + tid;
      int row = flat >> 4, f4 = flat & 15;
      float4 v = *(const float4*)(xblk + row * 512 + ng * 64 + f4 * 4);
      *(float4*)(EP + row * 68 + f4 * 4) = v;
    }
    LGKM0; BARR();
    float boA[2];
#pragma unroll
    for (int nt = 0; nt < 2; ++nt) boA[nt] = bo[ng * 64 + un * 32 + nt * 16 + l15];
#pragma unroll
    for (int mt = 0; mt < 2; ++mt)
#pragma unroll
      for (int nt = 0; nt < 2; ++nt)
#pragma unroll
        for (int r = 0; r < 4; ++r) {
          int row = um * 32 + mt * 16 + g * 4 + r;
          float xv = EP[row * 68 + un * 32 + nt * 16 + l15];
          float v = acc[ng][mt][nt][r] + boA[nt] + xv;
          acc[ng][mt][nt][r] = v;
          s1[mt][r] += v;
          s2[mt][r] += v * v;
        }
    LGKM0; BARR();
  }
#pragma unroll
  for (int mk = 1; mk < 16; mk <<= 1)
#pragma unroll
    for (int mt = 0; mt < 2; ++mt)
#pragma unroll
      for (int r = 0; r < 4; ++r) {
        s1[mt][r] += __shfl_xor(s1[mt][r], mk);
        s2[mt][r] += __shfl_xor(s2[mt][r], mk);
      }
  if (l15 == 0) {
#pragma unroll
    for (int mt = 0; mt < 2; ++mt)
#pragma unroll
      for (int r = 0; r < 4; ++r) {
        int row = um * 32 + mt * 16 + g * 4 + r;
        SM1[row * 2 + un] = s1[mt][r];
        SM2[row * 2 + un] = s2[mt][r];
      }
  }
  LGKM0; BARR();
  float mu[2][4], rs[2][4];
#pragma unroll
  for (int mt = 0; mt < 2; ++mt)
#pragma unroll
    for (int r = 0; r < 4; ++r) {
      int row = um * 32 + mt * 16 + g * 4 + r;
      float a1 = SM1[row * 2] + SM1[row * 2 + 1];
      float a2 = SM2[row * 2] + SM2[row * 2 + 1];
      float m = a1 * (1.0f / 512.0f);
      float var = a2 * (1.0f / 512.0f) - m * m;
      mu[mt][r] = m;
      rs[mt][r] = rsqrtf(var + 1e-5f);
    }
  BARR();
#pragma unroll
  for (int ng = 0; ng < 8; ++ng) {
    float lgA[2], lbA[2];
#pragma unroll
    for (int nt = 0; nt < 2; ++nt) {
      int col = ng * 64 + un * 32 + nt * 16 + l15;
      lgA[nt] = lng[col];
      lbA[nt] = lnb[col];
    }
#pragma unroll
    for (int mt = 0; mt < 2; ++mt)
#pragma unroll
      for (int nt = 0; nt < 2; ++nt)
#pragma unroll
        for (int r = 0; r < 4; ++r) {
          int row = um * 32 + mt * 16 + g * 4 + r;
          EP[row * 68 + un * 32 + nt * 16 + l15] =
              (acc[ng][mt][nt][r] - mu[mt][r]) * rs[mt][r] * lgA[nt] + lbA[nt];
        }
    LGKM0; BARR();
#pragma unroll
    for (int t = 0; t < 4; ++t) {
      int flat = t * 256 + tid;
      int row = flat >> 4, f4 = flat & 15;
      *(float4*)(oblk + row * 512 + ng * 64 + f4 * 4) =
          *(const float4*)(EP + row * 68 + f4 * 4);
    }
    BARR();
  }
}

// ============================ launch =======================================
extern "C" void kernel_launch(void* const* d_in, const int* in_sizes, int n_in,
                              void* d_out, int out_size, void* d_ws, size_t ws_size,
                              hipStream_t stream) {
  const float* x    = (const float*)d_in[0];
  const float* wqkv = (const float*)d_in[1];
  const float* bqkv = (const float*)d_in[2];
  const float* wo   = (const float*)d_in[3];
  const float* bo   = (const float*)d_in[4];
  const float* lng  = (const float*)d_in[5];
  const float* lnb  = (const float*)d_in[6];
  const float* rel  = (const float*)d_in[7];

  // ws: 192 QKV 8KB chunks [0,1572864) | 32 Wo 16KB chunks | bias2d @2097152
  unsigned short* wt = (unsigned short*)d_ws;
  float* bias2d = (float*)((char*)d_ws + 2097152);
  const char* wqc = (const char*)d_ws;
  const char* woc = (const char*)d_ws + 1572864;

  prep_kernel<<<8336, 256, 0, stream>>>(x, wqkv, wo, rel, wt, bias2d,
                                        (char*)d_out);
  attn_qkv<<<2048, 256, 0, stream>>>(wqc, bqkv, bias2d, (char*)d_out);
  oproj_ln<<<2048, 256, 0, stream>>>((const char*)d_out, woc, bo, x, lng, lnb,
                                     (float*)d_out);
}

// Round 11
// 550.699 us; speedup vs baseline: 2.1537x; 2.1537x over previous
//
#include <hip/hip_runtime.h>
#include <stdint.h>
#include <stddef.h>

// ---------------------------------------------------------------------------
// EnhancedSpatialAttention, round 11 (MI355X / gfx950).
// K2 = attn_qkv2: TWO sequences per block (512 thr, 8 waves = 2 seq-groups x 4)
// to halve the per-sequence weight streaming through L2 (r7-r9's invariant
// ~370us was L2-BW + per-body DMA bound at 1 seq/block).
//  - 8KB weight chunks (kc-major, r10 prep layout), ring-4, stage-3-ahead,
//    counted waits Q:vmcnt(2) K:none V:vmcnt(5) (derived from issue stream).
//  - x: unit-major bf16 chunks (prep'd into d_out back half), single 16KB LDS
//    x-stage (both seqs) staged once per kc at end of K body.
//  - per-wave: xa[8]=32 + acc 48 + b2d 16 VGPR -> fits 128 clamp, no spill.
//  - NO second __launch_bounds__ arg (r10 lesson: it wrecked the allocator).
// prep: verbatim r10. K3 oproj_ln: verbatim (HBM floor).
// ---------------------------------------------------------------------------

typedef __attribute__((ext_vector_type(8))) short short8;    // 8 bf16
typedef __attribute__((ext_vector_type(4))) float f32x4;     // MFMA C/D frag

typedef __attribute__((address_space(3))) unsigned int as3_u32;
typedef __attribute__((address_space(1))) unsigned int as1_u32;

#define VMCNT5  asm volatile("s_waitcnt vmcnt(5)" ::: "memory")
#define VMCNT2  asm volatile("s_waitcnt vmcnt(2)" ::: "memory")
#define VMCNT0  asm volatile("s_waitcnt vmcnt(0)" ::: "memory")
#define LGKM0   asm volatile("s_waitcnt lgkmcnt(0)" ::: "memory")
#define BARR()  __builtin_amdgcn_s_barrier()
#define PRIO1   __builtin_amdgcn_s_setprio(1)
#define PRIO0   __builtin_amdgcn_s_setprio(0)

__device__ __forceinline__ unsigned short f2bf(float f) {
  unsigned u = __builtin_bit_cast(unsigned, f);
  u = (u + 0x7FFFu + ((u >> 16) & 1u)) >> 16;   // RNE
  return (unsigned short)u;
}

__device__ __forceinline__ f32x4 mfma16(short8 a, short8 b, f32x4 c) {
  return __builtin_amdgcn_mfma_f32_16x16x32_bf16(a, b, c, 0, 0, 0);
}

// 64-row x 64-col bf16 scratch, 128B row stride, 16B-unit XOR swizzle.
__device__ __forceinline__ short8 rd8s(const char* buf, int row, int unit) {
  return *(const short8*)(buf + row * 128 + ((unit ^ (row & 7)) * 16));
}
__device__ __forceinline__ void wr2s(char* buf, int row, int col, unsigned short v) {
  int slot = (col >> 3) ^ (row & 7);
  *(unsigned short*)(buf + row * 128 + slot * 16 + (col & 7) * 2) = v;
}
__device__ __forceinline__ void wr8s(char* buf, int row, int col, uint2 v) {
  int slot = (col >> 3) ^ (row & 7);
  *(uint2*)(buf + row * 128 + slot * 16 + (col & 7) * 2) = v;
}

// 512-thread staging: one 8KB chunk, 1 global_load_lds per thread.
__device__ __forceinline__ void stage8w(char* lds, const char* gsrc, int w, int lane) {
  __builtin_amdgcn_global_load_lds((const as1_u32*)(gsrc + w * 1024 + lane * 16),
                                   (as3_u32*)(lds + w * 1024), 16, 0, 0);
}

// 256-thread staging (K3): one 16KB chunk, 4 per thread.
__device__ __forceinline__ void stage16k(char* ldsbase, const char* gsrc, int w, int lane) {
#pragma unroll
  for (int j = 0; j < 4; ++j) {
    int off = j * 4096 + w * 1024;
    __builtin_amdgcn_global_load_lds((const as1_u32*)(gsrc + off + lane * 16),
                                     (as3_u32*)(ldsbase + off), 16, 0, 0);
  }
}

// ============================ prep (verbatim r10) ==========================
__global__ void prep_kernel(const float* __restrict__ x,
                            const float* __restrict__ wqkv_f,
                            const float* __restrict__ wo_f,
                            const float* __restrict__ rel,
                            unsigned short* __restrict__ wt,
                            float* __restrict__ bias2d,
                            char* __restrict__ dout) {
  int b = blockIdx.x, tid = threadIdx.x;
  if (b < 8192) {
    int n = b >> 2, p = b & 3;
    char* dstb = dout + (size_t)n * 131072 + 65536;
    const float* srcb = x + (size_t)n * 32768;
#pragma unroll
    for (int t = 0; t < 4; ++t) {
      int flat = t * 256 + tid;
      int c = p * 2 + (flat >> 9);
      int r512 = flat & 511;
      int row = r512 >> 3, u = r512 & 7;
      const float* src = srcb + row * 512 + c * 64 + u * 8;
      float4 a = *(const float4*)src;
      float4 cc = *(const float4*)(src + 4);
      unsigned p0 = (unsigned)f2bf(a.x) | ((unsigned)f2bf(a.y) << 16);
      unsigned p1 = (unsigned)f2bf(a.z) | ((unsigned)f2bf(a.w) << 16);
      unsigned p2 = (unsigned)f2bf(cc.x) | ((unsigned)f2bf(cc.y) << 16);
      unsigned p3 = (unsigned)f2bf(cc.z) | ((unsigned)f2bf(cc.w) << 16);
      *(uint4*)(dstb + c * 8192 + u * 1024 + row * 16) = make_uint4(p0, p1, p2, p3);
    }
  } else if (b < 8288) {
    int cb2 = (b - 8192) * 2;
#pragma unroll
    for (int t = 0; t < 4; ++t) {
      int flat = t * 256 + tid;
      int c = cb2 + (flat >> 9);
      int r512 = flat & 511;
      int row = r512 >> 3, us = r512 & 7;
      int kg = us ^ (row & 7);
      int h = c / 24, j = c % 24;
      int kc = j / 3, rg = j % 3;
      const float* src =
          wqkv_f + (size_t)(rg * 512 + h * 64 + row) * 512 + kc * 64 + kg * 8;
      float4 a = *(const float4*)src;
      float4 cc = *(const float4*)(src + 4);
      unsigned p0 = (unsigned)f2bf(a.x) | ((unsigned)f2bf(a.y) << 16);
      unsigned p1 = (unsigned)f2bf(a.z) | ((unsigned)f2bf(a.w) << 16);
      unsigned p2 = (unsigned)f2bf(cc.x) | ((unsigned)f2bf(cc.y) << 16);
      unsigned p3 = (unsigned)f2bf(cc.z) | ((unsigned)f2bf(cc.w) << 16);
      *(uint4*)(wt + (size_t)c * 4096 + r512 * 8) = make_uint4(p0, p1, p2, p3);
    }
  } else if (b < 8320) {
    int cw = b - 8288;
    unsigned short* dst = wt + 786432 + (size_t)cw * 8192;
#pragma unroll
    for (int t = 0; t < 4; ++t) {
      int u = t * 256 + tid;
      int row = u >> 4, us = u & 15;
      int kg = (us & 8) | ((us ^ row) & 7);
      int kcw = cw >> 3, ng = cw & 7;
      const float* src = wo_f + (size_t)(ng * 64 + row) * 512 + kcw * 128 + kg * 8;
      float4 a = *(const float4*)src;
      float4 cc = *(const float4*)(src + 4);
      unsigned p0 = (unsigned)f2bf(a.x) | ((unsigned)f2bf(a.y) << 16);
      unsigned p1 = (unsigned)f2bf(a.z) | ((unsigned)f2bf(a.w) << 16);
      unsigned p2 = (unsigned)f2bf(cc.x) | ((unsigned)f2bf(cc.y) << 16);
      unsigned p3 = (unsigned)f2bf(cc.z) | ((unsigned)f2bf(cc.w) << 16);
      *(uint4*)(dst + u * 8) = make_uint4(p0, p1, p2, p3);
    }
  } else {
    int idx = (b - 8320) * 256 + tid;
    int m = idx >> 6, nn = idx & 63;
    float s = 0.f;
#pragma unroll
    for (int hh = 0; hh < 8; ++hh) s += rel[hh * 16384 + m * 128 + nn];
    bias2d[idx] = s * 0.125f;
  }
}

// ============================ K2: attn_qkv2 ================================
__global__ __launch_bounds__(512) void attn_qkv2(
    const char* __restrict__ wq,        // 192 x 8KB QKV chunks (kc-major)
    const float* __restrict__ bqkv,     // [1536]
    const float* __restrict__ bias2d,   // [64,64]
    char* __restrict__ ctxg) {          // d_out stripes: [ctx 64KB | xbf 64KB]
  extern __shared__ __attribute__((aligned(16))) char smem[];  // 104448 B
  char* RING = smem;                   // 4 x 8KB weight ring (slot = chunk&3)
  char* XB   = smem + 32768;           // 2 x 8KB x-chunk stage (seq0, seq1)
  char* SCb  = smem + 49152;           // 2 x 24KB attn scratch
  float* BQ  = (float*)(smem + 98304); // bqkv copy (6KB)

  const int tid = threadIdx.x;
  const int w = tid >> 6, lane = tid & 63;
  const int l15 = lane & 15, g = lane >> 4;
  const int ws = w >> 2;               // seq-group (0/1)
  const int wn = w & 3;                // N-group within seq (16 cols)
  const int n0 = blockIdx.x * 2;

  const char* x0 = ctxg + (size_t)n0 * 131072 + 65536;
  const char* x1 = x0 + 131072;
  char* B0 = SCb + ws * 24576;         // Q, then P
  char* B1 = B0 + 8192;                // K, then ctx
  char* B2 = B0 + 16384;               // V^T

  const int brow = wn * 16 + l15;      // weight out-col (B-frag LDS row)
  const int us0 = (g ^ (brow & 7)) * 16;
  const int us1 = ((4 + g) ^ (brow & 7)) * 16;
  const int mrow = wn * 16 + g * 4;    // attn C rows (within seq)
  const int wrow = wn * 16 + l15;      // attn A row

  // ---- preamble: bqkv -> LDS, bias2d -> regs, drain.
#pragma unroll
  for (int i = 0; i < 3; ++i) BQ[i * 512 + tid] = bqkv[i * 512 + tid];
  float b2d[16];
#pragma unroll
  for (int nt = 0; nt < 4; ++nt)
#pragma unroll
    for (int r = 0; r < 4; ++r)
      b2d[nt * 4 + r] = bias2d[(mrow + r) * 64 + nt * 16 + l15];
  VMCNT0; LGKM0; BARR();

  // prologue: X(0) then W0,W1,W2 (order matters for counted waits)
  stage8w(XB, x0, w, lane);
  stage8w(XB + 8192, x1, w, lane);
  stage8w(RING, wq, w, lane);
  stage8w(RING + 8192, wq + 8192, w, lane);
  stage8w(RING + 16384, wq + 16384, w, lane);

  for (int h = 0; h < 8; ++h) {
    f32x4 aq[4] = {}, ak[4] = {}, av[4] = {};
#pragma unroll
    for (int kc = 0; kc < 8; ++kc) {
      const int j = h * 24 + kc * 3;
      const int sQ = (kc * 3) & 3, sK = (kc * 3 + 1) & 3, sV = (kc * 3 + 2) & 3;
      const int tQ = (kc * 3 + 3) & 3, tK = (kc * 3 + 4) & 3, tV = (kc * 3 + 5) & 3;
      // ================= Q body: consume W(j) + X(kc) =================
      { int c = j + 3; if (c > 191) c = 191;
        stage8w(RING + tQ * 8192, wq + (size_t)c * 8192, w, lane); }
      VMCNT2; BARR();
      short8 xa[8];
      { const char* xb = XB + ws * 8192;
#pragma unroll
        for (int mt = 0; mt < 4; ++mt)
#pragma unroll
          for (int ks = 0; ks < 2; ++ks)
            xa[mt * 2 + ks] = *(const short8*)(xb + (ks * 4 + g) * 1024 +
                                               (mt * 16 + l15) * 16);
      }
      {
        const char* wsl = RING + sQ * 8192;
        short8 bf0 = *(const short8*)(wsl + brow * 128 + us0);
        short8 bf1 = *(const short8*)(wsl + brow * 128 + us1);
        PRIO1;
#pragma unroll
        for (int mt = 0; mt < 4; ++mt) {
          aq[mt] = mfma16(xa[mt * 2], bf0, aq[mt]);
          aq[mt] = mfma16(xa[mt * 2 + 1], bf1, aq[mt]);
        }
        PRIO0;
      }
      // ================= K body: consume W(j+1) (landed at Q's wait) ======
      { int c = j + 4; if (c > 191) c = 191;
        stage8w(RING + tK * 8192, wq + (size_t)c * 8192, w, lane); }
      BARR();
      {
        const char* wsl = RING + sK * 8192;
        short8 bf0 = *(const short8*)(wsl + brow * 128 + us0);
        short8 bf1 = *(const short8*)(wsl + brow * 128 + us1);
        PRIO1;
#pragma unroll
        for (int mt = 0; mt < 4; ++mt) {
          ak[mt] = mfma16(xa[mt * 2], bf0, ak[mt]);
          ak[mt] = mfma16(xa[mt * 2 + 1], bf1, ak[mt]);
        }
        PRIO0;
      }
      // stage X(kc+1) late in K body (xa reads of kc are long done)
      { int k2 = (kc + 1) & 7;
        stage8w(XB, x0 + (size_t)k2 * 8192, w, lane);
        stage8w(XB + 8192, x1 + (size_t)k2 * 8192, w, lane); }
      // ================= V body: consume W(j+2) =================
      { int c = j + 5; if (c > 191) c = 191;
        stage8w(RING + tV * 8192, wq + (size_t)c * 8192, w, lane); }
      VMCNT5; BARR();
      {
        const char* wsl = RING + sV * 8192;
        short8 bf0 = *(const short8*)(wsl + brow * 128 + us0);
        short8 bf1 = *(const short8*)(wsl + brow * 128 + us1);
        PRIO1;
#pragma unroll
        for (int mt = 0; mt < 4; ++mt) {
          av[mt] = mfma16(xa[mt * 2], bf0, av[mt]);
          av[mt] = mfma16(xa[mt * 2 + 1], bf1, av[mt]);
        }
        PRIO0;
      }
    }

    // ---------- head writeback: Q->B0, K->B1, Vt->B2 (per seq-group) ------
    {
      int col = wn * 16 + l15;
      float bq = BQ[h * 64 + col];
      float bk = BQ[512 + h * 64 + col];
      float bv = BQ[1024 + h * 64 + col];
#pragma unroll
      for (int mt = 0; mt < 4; ++mt) {
        int rowb = mt * 16 + g * 4;
#pragma unroll
        for (int r = 0; r < 4; ++r) {
          wr2s(B0, rowb + r, col, f2bf(aq[mt][r] + bq));
          wr2s(B1, rowb + r, col, f2bf(ak[mt][r] + bk));
        }
        unsigned short p0 = f2bf(av[mt][0] + bv);
        unsigned short p1 = f2bf(av[mt][1] + bv);
        unsigned short p2 = f2bf(av[mt][2] + bv);
        unsigned short p3 = f2bf(av[mt][3] + bv);
        unsigned lo = (unsigned)p0 | ((unsigned)p1 << 16);
        unsigned hi = (unsigned)p2 | ((unsigned)p3 << 16);
        wr8s(B2, col, rowb, make_uint2(lo, hi));   // Vt[d][tok]
      }
    }
    LGKM0; BARR();   // Q/K/Vt visible to the group's 4 waves

    // ---- scores + softmax: P -> B0 (wave-own rows)
    {
      f32x4 sc[4] = {};
      short8 aq0 = rd8s(B0, wrow, g);
      short8 aq1 = rd8s(B0, wrow, 4 + g);
#pragma unroll
      for (int nt = 0; nt < 4; ++nt)
        sc[nt] = mfma16(aq0, rd8s(B1, nt * 16 + l15, g), sc[nt]);
#pragma unroll
      for (int nt = 0; nt < 4; ++nt)
        sc[nt] = mfma16(aq1, rd8s(B1, nt * 16 + l15, 4 + g), sc[nt]);
      float mx[4] = {-1e30f, -1e30f, -1e30f, -1e30f};
#pragma unroll
      for (int nt = 0; nt < 4; ++nt)
#pragma unroll
        for (int r = 0; r < 4; ++r) {
          float v = sc[nt][r] * 0.125f + b2d[nt * 4 + r];
          sc[nt][r] = v;
          mx[r] = fmaxf(mx[r], v);
        }
#pragma unroll
      for (int mk = 1; mk < 16; mk <<= 1)
#pragma unroll
        for (int r = 0; r < 4; ++r) mx[r] = fmaxf(mx[r], __shfl_xor(mx[r], mk));
      float sm[4] = {0.f, 0.f, 0.f, 0.f};
#pragma unroll
      for (int nt = 0; nt < 4; ++nt)
#pragma unroll
        for (int r = 0; r < 4; ++r) {
          float e = __expf(sc[nt][r] - mx[r]);
          sc[nt][r] = e;
          sm[r] += e;
        }
#pragma unroll
      for (int mk = 1; mk < 16; mk <<= 1)
#pragma unroll
        for (int r = 0; r < 4; ++r) sm[r] += __shfl_xor(sm[r], mk);
      float inv[4];
#pragma unroll
      for (int r = 0; r < 4; ++r) inv[r] = 1.0f / sm[r];
#pragma unroll
      for (int nt = 0; nt < 4; ++nt)
#pragma unroll
        for (int r = 0; r < 4; ++r)
          wr2s(B0, mrow + r, nt * 16 + l15, f2bf(sc[nt][r] * inv[r]));
    }

    // ---- PV (P own rows in-wave; Vt stable since writeback barrier)
    f32x4 cv[4] = {};
    {
      short8 ap0 = rd8s(B0, wrow, g);
      short8 ap1 = rd8s(B0, wrow, 4 + g);
#pragma unroll
      for (int nt = 0; nt < 4; ++nt)
        cv[nt] = mfma16(ap0, rd8s(B2, nt * 16 + l15, g), cv[nt]);
#pragma unroll
      for (int nt = 0; nt < 4; ++nt)
        cv[nt] = mfma16(ap1, rd8s(B2, nt * 16 + l15, 4 + g), cv[nt]);
    }
    BARR();   // all waves' K reads (scores) done before ctx overwrites B1
#pragma unroll
    for (int nt = 0; nt < 4; ++nt)
#pragma unroll
      for (int r = 0; r < 4; ++r)
        wr2s(B1, mrow + r, nt * 16 + l15, f2bf(cv[nt][r]));
    LGKM0; BARR();

    // ---- ctx copyout: contiguous 8KB/head into stripe front half
    {
      char* cdst = ctxg + (size_t)(n0 + ws) * 131072 + h * 8192;
      int gt = tid & 255;
#pragma unroll
      for (int it = 0; it < 2; ++it) {
        int flat = it * 256 + gt;
        int row = flat >> 3, s = flat & 7;
        uint4 v = *(const uint4*)(B1 + row * 128 + s * 16);
        *(uint4*)(cdst + row * 128 + s * 16) = v;
      }
    }
  }
}

// ============================ K3: oproj_ln (verbatim) ======================
__global__ __launch_bounds__(256, 2) void oproj_ln(
    const char* __restrict__ ctxg,
    const char* __restrict__ wo,
    const float* __restrict__ bo,
    const float* __restrict__ x,
    const float* __restrict__ lng,
    const float* __restrict__ lnb,
    float* __restrict__ out) {
  __shared__ __attribute__((aligned(16))) char smem[65536];
  char* WB = smem;
  char* CB = smem + 32768;
  float* EP  = (float*)smem;
  float* SM1 = (float*)(smem + 32768);
  float* SM2 = (float*)(smem + 33408);

  const int n = blockIdx.x;
  const int tid = threadIdx.x;
  const int w = tid >> 6, lane = tid & 63;
  const int l15 = lane & 15, g = lane >> 4;
  const int um = w >> 1, un = w & 1;

  const char* cbase = ctxg + (size_t)n * 131072;

  stage16k(CB, cbase, w, lane);
  stage16k(WB, wo, w, lane);

  f32x4 acc[8][2][2] = {};

  for (int kc = 0; kc < 4; ++kc) {
    short8 actx[2][4];
#pragma unroll
    for (int ng = 0; ng < 8; ++ng) {
      int b = kc * 8 + ng;
      if (b < 31)
        stage16k(WB + (((b + 1) & 1) << 14), wo + (size_t)(b + 1) * 16384, w, lane);
      if ((ng & 1) == 0 && kc < 3) {
        int p = ng >> 1;
        int off = p * 4096 + w * 1024;
        __builtin_amdgcn_global_load_lds(
            (const as1_u32*)(cbase + (kc + 1) * 16384 + off + lane * 16),
            (as3_u32*)(CB + (((kc + 1) & 1) << 14) + off), 16, 0, 0);
      }
      if (b < 31) { VMCNT5; } else { VMCNT0; }
      BARR();
      const char* cb = CB + ((kc & 1) << 14);
      if (ng == 0) {
#pragma unroll
        for (int mt = 0; mt < 2; ++mt)
#pragma unroll
          for (int ks = 0; ks < 4; ++ks) {
            int row = um * 32 + mt * 16 + l15;
            int u = ks * 4 + g;
            actx[mt][ks] = *(const short8*)(cb + (u >> 3) * 8192 + row * 128 +
                                            (((u & 7) ^ (row & 7)) * 16));
          }
      }
      const char* wsl = WB + ((b & 1) << 14);
      PRIO1;
#pragma unroll
      for (int ks = 0; ks < 4; ++ks) {
#pragma unroll
        for (int nt = 0; nt < 2; ++nt) {
          int row = un * 32 + nt * 16 + l15;
          int kg = ks * 4 + g;
          int us = (kg & 8) | ((kg ^ row) & 7);
          short8 bfr = *(const short8*)(wsl + row * 256 + us * 16);
          acc[ng][0][nt] = mfma16(actx[0][ks], bfr, acc[ng][0][nt]);
          acc[ng][1][nt] = mfma16(actx[1][ks], bfr, acc[ng][1][nt]);
        }
      }
      PRIO0;
      BARR();
    }
  }

  VMCNT0;
  const float* xblk = x + (size_t)n * 32768;
  float* oblk = out + (size_t)n * 32768;
  float s1[2][4] = {}, s2[2][4] = {};

#pragma unroll
  for (int ng = 0; ng < 8; ++ng) {
#pragma unroll
    for (int t = 0; t < 4; ++t) {
      int flat = t * 256 + tid;
      int row = flat >> 4, f4 = flat & 15;
      float4 v = *(const float4*)(xblk + row * 512 + ng * 64 + f4 * 4);
      *(float4*)(EP + row * 68 + f4 * 4) = v;
    }
    LGKM0; BARR();
    float boA[2];
#pragma unroll
    for (int nt = 0; nt < 2; ++nt) boA[nt] = bo[ng * 64 + un * 32 + nt * 16 + l15];
#pragma unroll
    for (int mt = 0; mt < 2; ++mt)
#pragma unroll
      for (int nt = 0; nt < 2; ++nt)
#pragma unroll
        for (int r = 0; r < 4; ++r) {
          int row = um * 32 + mt * 16 + g * 4 + r;
          float xv = EP[row * 68 + un * 32 + nt * 16 + l15];
          float v = acc[ng][mt][nt][r] + boA[nt] + xv;
          acc[ng][mt][nt][r] = v;
          s1[mt][r] += v;
          s2[mt][r] += v * v;
        }
    LGKM0; BARR();
  }
#pragma unroll
  for (int mk = 1; mk < 16; mk <<= 1)
#pragma unroll
    for (int mt = 0; mt < 2; ++mt)
#pragma unroll
      for (int r = 0; r < 4; ++r) {
        s1[mt][r] += __shfl_xor(s1[mt][r], mk);
        s2[mt][r] += __shfl_xor(s2[mt][r], mk);
      }
  if (l15 == 0) {
#pragma unroll
    for (int mt = 0; mt < 2; ++mt)
#pragma unroll
      for (int r = 0; r < 4; ++r) {
        int row = um * 32 + mt * 16 + g * 4 + r;
        SM1[row * 2 + un] = s1[mt][r];
        SM2[row * 2 + un] = s2[mt][r];
      }
  }
  LGKM0; BARR();
  float mu[2][4], rs[2][4];
#pragma unroll
  for (int mt = 0; mt < 2; ++mt)
#pragma unroll
    for (int r = 0; r < 4; ++r) {
      int row = um * 32 + mt * 16 + g * 4 + r;
      float a1 = SM1[row * 2] + SM1[row * 2 + 1];
      float a2 = SM2[row * 2] + SM2[row * 2 + 1];
      float m = a1 * (1.0f / 512.0f);
      float var = a2 * (1.0f / 512.0f) - m * m;
      mu[mt][r] = m;
      rs[mt][r] = rsqrtf(var + 1e-5f);
    }
  BARR();
#pragma unroll
  for (int ng = 0; ng < 8; ++ng) {
    float lgA[2], lbA[2];
#pragma unroll
    for (int nt = 0; nt < 2; ++nt) {
      int col = ng * 64 + un * 32 + nt * 16 + l15;
      lgA[nt] = lng[col];
      lbA[nt] = lnb[col];
    }
#pragma unroll
    for (int mt = 0; mt < 2; ++mt)
#pragma unroll
      for (int nt = 0; nt < 2; ++nt)
#pragma unroll
        for (int r = 0; r < 4; ++r) {
          int row = um * 32 + mt * 16 + g * 4 + r;
          EP[row * 68 + un * 32 + nt * 16 + l15] =
              (acc[ng][mt][nt][r] - mu[mt][r]) * rs[mt][r] * lgA[nt] + lbA[nt];
        }
    LGKM0; BARR();
#pragma unroll
    for (int t = 0; t < 4; ++t) {
      int flat = t * 256 + tid;
      int row = flat >> 4, f4 = flat & 15;
      *(float4*)(oblk + row * 512 + ng * 64 + f4 * 4) =
          *(const float4*)(EP + row * 68 + f4 * 4);
    }
    BARR();
  }
}

// ============================ launch =======================================
extern "C" void kernel_launch(void* const* d_in, const int* in_sizes, int n_in,
                              void* d_out, int out_size, void* d_ws, size_t ws_size,
                              hipStream_t stream) {
  const float* x    = (const float*)d_in[0];
  const float* wqkv = (const float*)d_in[1];
  const float* bqkv = (const float*)d_in[2];
  const float* wo   = (const float*)d_in[3];
  const float* bo   = (const float*)d_in[4];
  const float* lng  = (const float*)d_in[5];
  const float* lnb  = (const float*)d_in[6];
  const float* rel  = (const float*)d_in[7];

  // ws: 192 QKV 8KB chunks [0,1572864) | 32 Wo 16KB chunks | bias2d @2097152
  unsigned short* wt = (unsigned short*)d_ws;
  float* bias2d = (float*)((char*)d_ws + 2097152);
  const char* wqc = (const char*)d_ws;
  const char* woc = (const char*)d_ws + 1572864;

  hipFuncSetAttribute(reinterpret_cast<const void*>(attn_qkv2),
                      hipFuncAttributeMaxDynamicSharedMemorySize, 104448);

  prep_kernel<<<8336, 256, 0, stream>>>(x, wqkv, wo, rel, wt, bias2d,
                                        (char*)d_out);
  attn_qkv2<<<1024, 512, 104448, stream>>>(wqc, bqkv, bias2d, (char*)d_out);
  oproj_ln<<<2048, 256, 0, stream>>>((const char*)d_out, woc, bo, x, lng, lnb,
                                     (float*)d_out);
}